// Round 4
// baseline (87.376 us; speedup 1.0000x reference)
//
#include <hip/hip_runtime.h>

// QuantumVQCHead, single fused kernel.
//   a = h @ W_pre^T + b ; angle = tanh(a)*pi/2 ; 8-qubit VQC (RY embed,
//   RX/RY/RZ layer, CNOT ring) ; 24 Pauli expectations ; L2-normalize.
//
// Analytic reduction (verified, passed R1/R2): product state + Clifford ring
//   => every observable is a product of per-qubit Bloch components:
//   X[w]=Xw*X{w+1} (w<7), X[7]=X7*X0*X1
//   Y[0]=X0*Y1*Z2..Z7 ; Y[w]=Yw*X{w+1}*Z0..Z{w-1} (1<=w<=6)
//   Y[7]=-Y7*Y0*Y1*Z2..Z6 ; Z[0]=Z1..Z7 ; Z[w>=1]=Z0..Zw
//
// Layout: wave handles 8 rows. Lane covers cols [lane*8,lane*8+8) for the
// GEMV; log-halving shuffle reduce (10 shfl/row) leaves dot(row r, qubit
// lane>>3) in v[r]; select+bpermute transpose puts all 8 dots of row r on
// lane r; lanes 0..7 run the scalar epilogue and store 6 float4 each.

__global__ __launch_bounds__(256) void vqc_fused(
    const float* __restrict__ h,    // [B,512]
    const float* __restrict__ Wp,   // [8,512]
    const float* __restrict__ bp,   // [8]
    const float* __restrict__ wt,   // [1,8,3]
    float* __restrict__ out,        // [B,24]
    int B)
{
    const int lane = threadIdx.x & 63;
    const int wave = (blockIdx.x * blockDim.x + threadIdx.x) >> 6;
    const int row0 = wave * 8;
    if (row0 >= B) return;

    // ---- W slice: lane's 8 columns for all 8 qubits (16 KB/wave, L1-hot) ----
    const float4* W4 = (const float4*)Wp;
    float wf[8][8];
    #pragma unroll
    for (int q = 0; q < 8; ++q) {
        float4 v0 = W4[q * 128 + lane * 2 + 0];
        float4 v1 = W4[q * 128 + lane * 2 + 1];
        wf[q][0] = v0.x; wf[q][1] = v0.y; wf[q][2] = v0.z; wf[q][3] = v0.w;
        wf[q][4] = v1.x; wf[q][5] = v1.y; wf[q][6] = v1.z; wf[q][7] = v1.w;
    }

    // ---- hoist all 8 rows' h loads (16 float4 in flight) ----
    const float4* H4 = (const float4*)h;
    float4 ha[8], hb[8];
    #pragma unroll
    for (int r = 0; r < 8; ++r) {
        ha[r] = H4[(row0 + r) * 128 + lane * 2 + 0];
        hb[r] = H4[(row0 + r) * 128 + lane * 2 + 1];
    }

    const int b3 = (lane >> 3) & 1, b4 = (lane >> 4) & 1, b5 = (lane >> 5) & 1;

    float v[8];   // v[r] = dot(row0+r, qubit lane>>3), replicated in group
    #pragma unroll
    for (int r = 0; r < 8; ++r) {
        float hf[8] = { ha[r].x, ha[r].y, ha[r].z, ha[r].w,
                        hb[r].x, hb[r].y, hb[r].z, hb[r].w };
        float acc[8];
        #pragma unroll
        for (int q = 0; q < 8; ++q) {
            float a = 0.f;
            #pragma unroll
            for (int j = 0; j < 8; ++j) a = fmaf(wf[q][j], hf[j], a);
            acc[q] = a;
        }
        // log-halving reduce across lane bits 3..5 (verified in R2)
        float n[4];
        #pragma unroll
        for (int j = 0; j < 4; ++j) {
            float k = b3 ? acc[1 + 2 * j] : acc[0 + 2 * j];
            float s = b3 ? acc[0 + 2 * j] : acc[1 + 2 * j];
            n[j] = k + __shfl_xor(s, 8);
        }
        float m[2];
        #pragma unroll
        for (int i = 0; i < 2; ++i) {
            float k = b4 ? n[1 + 2 * i] : n[0 + 2 * i];
            float s = b4 ? n[0 + 2 * i] : n[1 + 2 * i];
            m[i] = k + __shfl_xor(s, 16);
        }
        float k = b5 ? m[1] : m[0];
        float s = b5 ? m[0] : m[1];
        float vv = k + __shfl_xor(s, 32);
        vv += __shfl_xor(vv, 1);
        vv += __shfl_xor(vv, 2);
        vv += __shfl_xor(vv, 4);
        v[r] = vv;
    }

    // ---- transpose: lane l <- (row l&7, qubit l>>3), then gather row's dots ----
    float t = v[0];
    #pragma unroll
    for (int k2 = 1; k2 < 8; ++k2) t = ((lane & 7) == k2) ? v[k2] : t;

    float av[8];  // on lane r (<8): av[q] = dot(row0+r, qubit q)
    #pragma unroll
    for (int q = 0; q < 8; ++q) av[q] = __shfl(t, q * 8 + (lane & 7));

    // ---- scalar epilogue on lanes 0..7 (one row each; verified in R2) ----
    if (lane < 8 && row0 + lane < B) {
        const int row = row0 + lane;

        float X[8], Y[8], Z[8];
        #pragma unroll
        for (int q = 0; q < 8; ++q) {
            float t0 = wt[q * 3 + 0] * 0.5f;
            float t1 = wt[q * 3 + 1] * 0.5f;
            float t2 = wt[q * 3 + 2] * 0.5f;
            float s0, c0, s1, c1, sz, cz;
            __sincosf(t0, &s0, &c0);
            __sincosf(t1, &s1, &c1);
            __sincosf(t2, &sz, &cz);
            float N00r =  c1 * c0, N00i =  s1 * s0;
            float N01r = -s1 * c0, N01i = -c1 * s0;
            float N10r =  s1 * c0, N10i = -c1 * s0;
            float N11r =  c1 * c0, N11i = -s1 * s0;
            float M00r = cz * N00r + sz * N00i, M00i = cz * N00i - sz * N00r;
            float M01r = cz * N01r + sz * N01i, M01i = cz * N01i - sz * N01r;
            float M10r = cz * N10r - sz * N10i, M10i = cz * N10i + sz * N10r;
            float M11r = cz * N11r - sz * N11i, M11i = cz * N11i + sz * N11r;

            float a = av[q] + bp[q];
            a = fminf(fmaxf(a, -15.f), 15.f);
            float e = __expf(a + a);
            float th = (e - 1.f) / (e + 1.f);          // tanh(a)
            float phi = th * 0.78539816339744831f;     // tanh(a)*(pi/2)/2
            float ss, cc;
            __sincosf(phi, &ss, &cc);
            float ar = M00r * cc + M01r * ss, ai = M00i * cc + M01i * ss;
            float br = M10r * cc + M11r * ss, bi = M10i * cc + M11i * ss;
            Z[q] = (ar * ar + ai * ai) - (br * br + bi * bi);
            X[q] = 2.f * (ar * br + ai * bi);
            Y[q] = 2.f * (ar * bi - ai * br);
        }

        float P[8], T[8];
        P[0] = Z[0];
        #pragma unroll
        for (int w = 1; w < 8; ++w) P[w] = P[w - 1] * Z[w];
        T[7] = Z[7];
        #pragma unroll
        for (int w = 6; w >= 0; --w) T[w] = Z[w] * T[w + 1];
        float Z2to6 = Z[2] * Z[3] * Z[4] * Z[5] * Z[6];

        float o[24];
        #pragma unroll
        for (int w = 0; w < 7; ++w) o[3 * w] = X[w] * X[w + 1];
        o[21] = X[7] * X[0] * X[1];
        o[1] = X[0] * Y[1] * T[2];
        #pragma unroll
        for (int w = 1; w < 7; ++w) o[3 * w + 1] = Y[w] * X[w + 1] * P[w - 1];
        o[22] = -Y[7] * Y[0] * Y[1] * Z2to6;
        o[2] = T[1];
        #pragma unroll
        for (int w = 1; w < 8; ++w) o[3 * w + 2] = P[w];

        float sq = 0.f;
        #pragma unroll
        for (int j = 0; j < 24; ++j) sq = fmaf(o[j], o[j], sq);
        float inv = 1.f / fmaxf(sqrtf(sq), 1e-12f);

        float4* O4 = (float4*)(out + row * 24);
        #pragma unroll
        for (int j = 0; j < 6; ++j) {
            float4 vv = { o[4 * j] * inv, o[4 * j + 1] * inv,
                          o[4 * j + 2] * inv, o[4 * j + 3] * inv };
            O4[j] = vv;
        }
    }
}

extern "C" void kernel_launch(void* const* d_in, const int* in_sizes, int n_in,
                              void* d_out, int out_size, void* d_ws, size_t ws_size,
                              hipStream_t stream) {
    const float* h  = (const float*)d_in[0];
    const float* Wp = (const float*)d_in[1];
    const float* bp = (const float*)d_in[2];
    const float* wt = (const float*)d_in[3];
    float* out = (float*)d_out;

    const int B = in_sizes[0] / 512;         // 16384
    const int waves = (B + 7) / 8;           // 8 rows per wave
    const int nblk = (waves + 3) / 4;        // 4 waves per 256-thread block = 512
    vqc_fused<<<nblk, 256, 0, stream>>>(h, Wp, bp, wt, out, B);
}

// Round 5
// 83.486 us; speedup vs baseline: 1.0466x; 1.0466x over previous
//
#include <hip/hip_runtime.h>

// QuantumVQCHead, two-stage (best-measured structure, R2, with exact grid):
//   Stage 1: a = h @ W_pre^T  (16384x512 @ 512x8 f32 GEMV) -> d_ws, 4 rows/wave
//   Stage 2: per-row scalar epilogue: tanh/clip angle, single-qubit Bloch
//            components, Pauli-propagated observables, L2-normalize.
//
// Observable algebra (verified by stabilizer conjugation, passing R1-R3):
//   X[w]=Xw*X{w+1} (w<7), X[7]=X7*X0*X1
//   Y[0]=X0*Y1*Z2..Z7 ; Y[w]=Yw*X{w+1}*Z0..Z{w-1} (1<=w<=6)
//   Y[7]=-Y7*Y0*Y1*Z2..Z6 ; Z[0]=Z1..Z7 ; Z[w>=1]=Z0..Zw

__global__ __launch_bounds__(256) void vqc_gemv(
    const float* __restrict__ h,    // [B,512]
    const float* __restrict__ Wp,   // [8,512]
    float* __restrict__ aw,         // [B,8] raw dots (no bias)
    int B)
{
    const int lane = threadIdx.x & 63;
    const int wave = (blockIdx.x * blockDim.x + threadIdx.x) >> 6;
    const int row0 = wave * 4;
    if (row0 >= B) return;

    // lane covers columns [lane*8, lane*8+8)
    const float4* W4 = (const float4*)Wp;
    float wf[8][8];
    #pragma unroll
    for (int q = 0; q < 8; ++q) {
        float4 v0 = W4[q * 128 + lane * 2 + 0];
        float4 v1 = W4[q * 128 + lane * 2 + 1];
        wf[q][0] = v0.x; wf[q][1] = v0.y; wf[q][2] = v0.z; wf[q][3] = v0.w;
        wf[q][4] = v1.x; wf[q][5] = v1.y; wf[q][6] = v1.z; wf[q][7] = v1.w;
    }

    // hoist all 4 rows' h loads (8 float4 in flight)
    const float4* H4 = (const float4*)h;
    float4 ha[4], hb[4];
    #pragma unroll
    for (int r = 0; r < 4; ++r) {
        ha[r] = H4[(row0 + r) * 128 + lane * 2 + 0];
        hb[r] = H4[(row0 + r) * 128 + lane * 2 + 1];
    }

    const int b3 = (lane >> 3) & 1, b4 = (lane >> 4) & 1, b5 = (lane >> 5) & 1;

    #pragma unroll
    for (int r = 0; r < 4; ++r) {
        float hf[8] = { ha[r].x, ha[r].y, ha[r].z, ha[r].w,
                        hb[r].x, hb[r].y, hb[r].z, hb[r].w };
        float acc[8];
        #pragma unroll
        for (int q = 0; q < 8; ++q) {
            float a = 0.f;
            #pragma unroll
            for (int j = 0; j < 8; ++j) a = fmaf(wf[q][j], hf[j], a);
            acc[q] = a;
        }
        // log-halving reduce: distribute 8 accs over lane bits 3..5 (10 shfl/row)
        float n[4];
        #pragma unroll
        for (int j = 0; j < 4; ++j) {
            float k = b3 ? acc[1 + 2 * j] : acc[0 + 2 * j];
            float s = b3 ? acc[0 + 2 * j] : acc[1 + 2 * j];
            n[j] = k + __shfl_xor(s, 8);
        }
        float m[2];
        #pragma unroll
        for (int i = 0; i < 2; ++i) {
            float k = b4 ? n[1 + 2 * i] : n[0 + 2 * i];
            float s = b4 ? n[0 + 2 * i] : n[1 + 2 * i];
            m[i] = k + __shfl_xor(s, 16);
        }
        float k = b5 ? m[1] : m[0];
        float s = b5 ? m[0] : m[1];
        float v = k + __shfl_xor(s, 32);
        v += __shfl_xor(v, 1);
        v += __shfl_xor(v, 2);
        v += __shfl_xor(v, 4);

        if ((lane & 7) == 0) aw[(row0 + r) * 8 + (lane >> 3)] = v;
    }
}

__global__ __launch_bounds__(256) void vqc_epilogue(
    const float* __restrict__ aw,   // [B,8]
    const float* __restrict__ bp,   // [8]
    const float* __restrict__ wt,   // [1,8,3]
    float* __restrict__ out,        // [B,24]
    int B)
{
    const int row = blockIdx.x * blockDim.x + threadIdx.x;
    if (row >= B) return;

    const float4* A4 = (const float4*)aw;
    float4 a0 = A4[row * 2 + 0];
    float4 a1 = A4[row * 2 + 1];
    float av[8] = { a0.x, a0.y, a0.z, a0.w, a1.x, a1.y, a1.z, a1.w };

    float X[8], Y[8], Z[8];
    #pragma unroll
    for (int q = 0; q < 8; ++q) {
        // batch-constant single-qubit matrix M = RZ(t2)RY(t1)RX(t0)
        float t0 = wt[q * 3 + 0] * 0.5f;
        float t1 = wt[q * 3 + 1] * 0.5f;
        float t2 = wt[q * 3 + 2] * 0.5f;
        float s0, c0, s1, c1, sz, cz;
        __sincosf(t0, &s0, &c0);
        __sincosf(t1, &s1, &c1);
        __sincosf(t2, &sz, &cz);
        float N00r =  c1 * c0, N00i =  s1 * s0;
        float N01r = -s1 * c0, N01i = -c1 * s0;
        float N10r =  s1 * c0, N10i = -c1 * s0;
        float N11r =  c1 * c0, N11i = -s1 * s0;
        float M00r = cz * N00r + sz * N00i, M00i = cz * N00i - sz * N00r;
        float M01r = cz * N01r + sz * N01i, M01i = cz * N01i - sz * N01r;
        float M10r = cz * N10r - sz * N10i, M10i = cz * N10i + sz * N10r;
        float M11r = cz * N11r - sz * N11i, M11i = cz * N11i + sz * N11r;

        float a = av[q] + bp[q];
        a = fminf(fmaxf(a, -15.f), 15.f);
        float e = __expf(a + a);
        float th = (e - 1.f) / (e + 1.f);          // tanh(a)
        float phi = th * 0.78539816339744831f;     // tanh(a)*(pi/2)/2
        float ss, cc;
        __sincosf(phi, &ss, &cc);
        float ar = M00r * cc + M01r * ss, ai = M00i * cc + M01i * ss;
        float br = M10r * cc + M11r * ss, bi = M10i * cc + M11i * ss;
        Z[q] = (ar * ar + ai * ai) - (br * br + bi * bi);
        X[q] = 2.f * (ar * br + ai * bi);
        Y[q] = 2.f * (ar * bi - ai * br);
    }

    // prefix P[w] = Z0..Zw ; suffix T[w] = Zw..Z7
    float P[8], T[8];
    P[0] = Z[0];
    #pragma unroll
    for (int w = 1; w < 8; ++w) P[w] = P[w - 1] * Z[w];
    T[7] = Z[7];
    #pragma unroll
    for (int w = 6; w >= 0; --w) T[w] = Z[w] * T[w + 1];
    float Z2to6 = Z[2] * Z[3] * Z[4] * Z[5] * Z[6];

    float o[24];
    #pragma unroll
    for (int w = 0; w < 7; ++w) o[3 * w] = X[w] * X[w + 1];
    o[21] = X[7] * X[0] * X[1];
    o[1] = X[0] * Y[1] * T[2];
    #pragma unroll
    for (int w = 1; w < 7; ++w) o[3 * w + 1] = Y[w] * X[w + 1] * P[w - 1];
    o[22] = -Y[7] * Y[0] * Y[1] * Z2to6;
    o[2] = T[1];
    #pragma unroll
    for (int w = 1; w < 8; ++w) o[3 * w + 2] = P[w];

    float sq = 0.f;
    #pragma unroll
    for (int j = 0; j < 24; ++j) sq = fmaf(o[j], o[j], sq);
    float inv = 1.f / fmaxf(sqrtf(sq), 1e-12f);

    float4* O4 = (float4*)(out + row * 24);
    #pragma unroll
    for (int j = 0; j < 6; ++j) {
        float4 vv = { o[4 * j] * inv, o[4 * j + 1] * inv,
                      o[4 * j + 2] * inv, o[4 * j + 3] * inv };
        O4[j] = vv;
    }
}

extern "C" void kernel_launch(void* const* d_in, const int* in_sizes, int n_in,
                              void* d_out, int out_size, void* d_ws, size_t ws_size,
                              hipStream_t stream) {
    const float* h  = (const float*)d_in[0];
    const float* Wp = (const float*)d_in[1];
    const float* bp = (const float*)d_in[2];
    const float* wt = (const float*)d_in[3];
    float* out = (float*)d_out;
    float* aw  = (float*)d_ws;               // [B,8] scratch

    const int B = in_sizes[0] / 512;         // 16384
    const int waves = (B + 3) / 4;           // 4 rows per wave -> 4096 waves
    const int nblk1 = (waves + 3) / 4;       // 4 waves/block -> 1024 blocks
    vqc_gemv<<<nblk1, 256, 0, stream>>>(h, Wp, aw, B);
    vqc_epilogue<<<(B + 255) / 256, 256, 0, stream>>>(aw, bp, wt, out, B);
}